// Round 1
// 420.636 us; speedup vs baseline: 1.0410x; 1.0410x over previous
//
#include <hip/hip_runtime.h>

typedef __bf16 bf16x8 __attribute__((ext_vector_type(8)));
typedef float f32x4 __attribute__((ext_vector_type(4)));

__device__ __forceinline__ unsigned short f2bf(float f) {
    union { float f; unsigned u; } v; v.f = f;
    unsigned r = v.u + 0x7FFFu + ((v.u >> 16) & 1u);   // round-to-nearest-even
    return (unsigned short)(r >> 16);
}

// ---------------------------------------------------------------------------
// Per-batch mask compaction: kidx[b][j] = j-th active k index; cnt[b]; padded[b]
// ---------------------------------------------------------------------------
__global__ __launch_bounds__(256) void mask_scan_kernel(
    const int* __restrict__ mask, int* __restrict__ kidx,
    int* __restrict__ cnt, int* __restrict__ padded)
{
    const int b = blockIdx.x;
    const int* m = mask + b * 1024;
    const int t = threadIdx.x;
    int v[4]; int s = 0;
#pragma unroll
    for (int e = 0; e < 4; e++) { v[e] = (m[t * 4 + e] != 0) ? 1 : 0; s += v[e]; }
    const int lane = t & 63, wv = t >> 6;
    int x = s;
#pragma unroll
    for (int off = 1; off < 64; off <<= 1) {
        int y = __shfl_up(x, off, 64);
        if (lane >= off) x += y;
    }
    __shared__ int wsum[4];
    if (lane == 63) wsum[wv] = x;
    __syncthreads();
    int base = 0;
    for (int w = 0; w < wv; w++) base += wsum[w];
    int pos = base + x - s;   // exclusive prefix
#pragma unroll
    for (int e = 0; e < 4; e++)
        if (v[e]) kidx[b * 1024 + pos++] = t * 4 + e;
    if (t == 255) {
        int total = base + x;
        cnt[b] = total;
        padded[b] = (total + 127) & ~127;
    }
}

// ---------------------------------------------------------------------------
// Both weight transposes in one dispatch: fp32 [512,512] -> bf16 [512,512]^T
// ---------------------------------------------------------------------------
__global__ __launch_bounds__(256) void transpose_w_kernel(
    const float* __restrict__ W0, const float* __restrict__ W1,
    unsigned short* __restrict__ D0, unsigned short* __restrict__ D1)
{
    __shared__ float tile[32][33];
    const float* src = blockIdx.z ? W1 : W0;
    unsigned short* dst = blockIdx.z ? D1 : D0;
    const int s0 = blockIdx.x * 32, d0 = blockIdx.y * 32;
    const int t = threadIdx.x, tr = t >> 5, tc = t & 31;
#pragma unroll
    for (int i = 0; i < 4; i++)
        tile[tr + i * 8][tc] = src[(size_t)(s0 + tr + i * 8) * 512 + d0 + tc];
    __syncthreads();
#pragma unroll
    for (int i = 0; i < 4; i++)
        dst[(size_t)(d0 + tr + i * 8) * 512 + s0 + tc] = f2bf(tile[tc][tr + i * 8]);
}

// ---------------------------------------------------------------------------
// Gather active memory rows (fp32 -> bf16) + transposed copy
// ---------------------------------------------------------------------------
__global__ __launch_bounds__(256) void gather_mem_kernel(
    const float* __restrict__ memory, const int* __restrict__ kidx,
    const int* __restrict__ cnt, const int* __restrict__ padded,
    unsigned short* __restrict__ MemG, unsigned short* __restrict__ MemGT)
{
    const int b = blockIdx.z;
    const int j0 = blockIdx.x * 32, d0 = blockIdx.y * 32;
    if (j0 >= padded[b]) return;
    const int nb = cnt[b];
    __shared__ float tile[32][33];
    const float* src = memory + (size_t)b * 1024 * 512;
    const int t = threadIdx.x, tr = t >> 5, tc = t & 31;
#pragma unroll
    for (int i = 0; i < 4; i++) {
        int j = j0 + tr + i * 8;
        float v = 0.f;
        if (j < nb) v = src[(size_t)kidx[b * 1024 + j] * 512 + d0 + tc];
        tile[tr + i * 8][tc] = v;
        MemG[(size_t)b * 1024 * 512 + (size_t)j * 512 + d0 + tc] = f2bf(v);
    }
    __syncthreads();
#pragma unroll
    for (int i = 0; i < 4; i++) {
        int d = d0 + tr + i * 8;
        MemGT[(size_t)b * 512 * 1024 + (size_t)d * 1024 + j0 + tc] = f2bf(tile[tc][tr + i * 8]);
    }
}

// ---------------------------------------------------------------------------
// Fused: inputs fp32 -> bf16 AND out[..., 512:1024] = inputs
// ---------------------------------------------------------------------------
__global__ __launch_bounds__(256) void fuse_inputs_kernel(
    const float4* __restrict__ in, uint2* __restrict__ in_bf16, float4* __restrict__ out)
{
    int i = blockIdx.x * 256 + threadIdx.x;   // 4194304 float4s total
    int bq = i >> 7;
    int d  = i & 127;
    float4 v = in[i];
    out[(size_t)bq * 256 + 128 + d] = v;
    union { unsigned short u[4]; uint2 p; } pk;
    pk.u[0] = f2bf(v.x); pk.u[1] = f2bf(v.y);
    pk.u[2] = f2bf(v.z); pk.u[3] = f2bf(v.w);
    in_bf16[i] = pk.p;
}

// ---------------------------------------------------------------------------
// 256x256-tile, 8-wave, BK=64, 8-phase bf16 GEMM  C = A @ Bt^T
//   A: [M,K] lda, Bt: [N,K] ldb (row-major), both bf16.
//   LDS: 2 buffers x (A 32K + B 32K), each tile split into K-halves of 16 KiB.
//   Swizzle: 16B slot within a 64B row XORed with (row>>1)&3, applied on the
//   GLOBAL source address (linear global_load_lds dest) and on ds_read addrs.
//   Counted vmcnt(4) at ends of phases 1 and 3; never drains to 0 mid-loop.
// CMODE 0: relu -> bf16
// CMODE 1: p = (col<cnt[z]) ? exp(acc*scale) : 0 -> bf16; rowsum += p (atomics)
// CMODE 2: acc / rowsum[row] -> fp32
// ---------------------------------------------------------------------------
template<int CMODE, int LIMA, int LIMB, int KDYN>
__global__ __launch_bounds__(512, 2) void gemm256(
    const unsigned short* __restrict__ A, const unsigned short* __restrict__ Bt,
    void* __restrict__ Cptr, int K, int lda, int ldb, float scale,
    const int* __restrict__ cnt, const int* __restrict__ padded,
    float* __restrict__ rowsum,
    long long aStride, long long bStride, long long cStride, int ldc)
{
    const int z = blockIdx.z;
    const int rowA = blockIdx.y * 256;
    const int rowB = blockIdx.x * 256;
    if (LIMA && rowA >= padded[z]) return;
    if (LIMB && rowB >= padded[z]) return;
    const int Kz = KDYN ? padded[z] : K;
    const int nt = Kz >> 6;                 // K-tiles of 64 (K is a multiple of 64)

    __shared__ __align__(16) unsigned char lds[131072];

    const int t = threadIdx.x;
    const int w = t >> 6;                   // wave 0..7
    const int lane = t & 63;
    const int wm = w >> 2;                  // 0..1 (M half)
    const int wn = w & 3;                   // 0..3 (N quarter)
    const int l15 = lane & 15;
    // phys 16B-slot byte offset for fragment reads (swizzled)
    const int sx = (((lane >> 4) ^ ((l15 >> 1) & 3)) << 4);

    const unsigned short* Ab = A + (size_t)z * aStride;
    const unsigned short* Bb = Bt + (size_t)z * bStride;

    // ---- staging: thread t covers linear LDS bytes [t*16) and [t*16+8192) of
    // each 16 KiB half-tile; source pre-swizzled so swizzled reads see logical data.
    const int r0 = t >> 2;                          // row 0..127 (and +128 for 2nd load)
    const int sl = (t & 3) ^ ((t >> 3) & 3);        // logical k-slot for this dest
    const unsigned short* aS0 = Ab + (size_t)(rowA + r0) * lda + sl * 8;
    const unsigned short* aS1 = aS0 + (size_t)128 * lda;
    const unsigned short* bS0 = Bb + (size_t)(rowB + r0) * ldb + sl * 8;
    const unsigned short* bS1 = bS0 + (size_t)128 * ldb;

    const int wofs = w * 1024;                      // wave-uniform LDS dest base
    // fragment read bases (byte offsets; add mf/nf*1024 + kh*16384 + buf*65536)
    const int aRd = (wm * 128 + l15) * 64 + sx;
    const int bRd = 32768 + (wn * 64 + l15) * 64 + sx;

    f32x4 acc[8][4];
#pragma unroll
    for (int i = 0; i < 8; i++)
#pragma unroll
        for (int j = 0; j < 4; j++) acc[i][j] = f32x4{0.f, 0.f, 0.f, 0.f};

#define GLL(SRC, DOFS) __builtin_amdgcn_global_load_lds(                        \
        (const __attribute__((address_space(1))) void*)(SRC),                   \
        (__attribute__((address_space(3))) void*)&lds[DOFS], 16, 0, 0)
#define STAGEA(BUF, KH, KEL) do {                                               \
        GLL(aS0 + (KEL), (BUF) * 65536 + (KH) * 16384 + wofs);                  \
        GLL(aS1 + (KEL), (BUF) * 65536 + (KH) * 16384 + wofs + 8192); } while (0)
#define STAGEB(BUF, KH, KEL) do {                                               \
        GLL(bS0 + (KEL), (BUF) * 65536 + 32768 + (KH) * 16384 + wofs);          \
        GLL(bS1 + (KEL), (BUF) * 65536 + 32768 + (KH) * 16384 + wofs + 8192); } while (0)

    // prologue: stage tile 0 (H0=A-klo, H1=B-klo, H2=A-khi, H3=B-khi)
    STAGEA(0, 0, 0); STAGEB(0, 0, 0); STAGEA(0, 1, 32); STAGEB(0, 1, 32);
    asm volatile("s_waitcnt vmcnt(4)" ::: "memory");   // H0,H1 of tile0 landed
    __builtin_amdgcn_s_barrier();

    for (int tt = 0; tt < nt; ++tt) {
        const int cur = (tt & 1) * 65536;
        const int nxt = (tt & 1) ^ 1;
        const bool pf = (tt + 1) < nt;
        const int kn = (tt + 1) * 64;
        bf16x8 af[4], bf0[4], bf1[4];

        // ---------- phase 0: kh=0, acc rows 0-3 ----------
#pragma unroll
        for (int i = 0; i < 4; i++) af[i]  = *(const bf16x8*)&lds[cur + aRd + i * 1024];
#pragma unroll
        for (int j = 0; j < 4; j++) bf0[j] = *(const bf16x8*)&lds[cur + bRd + j * 1024];
        if (pf) STAGEA(nxt, 0, kn);
        __builtin_amdgcn_s_barrier();
        asm volatile("s_waitcnt lgkmcnt(0)" ::: "memory");
        __builtin_amdgcn_sched_barrier(0);
        __builtin_amdgcn_s_setprio(1);
#pragma unroll
        for (int i = 0; i < 4; i++)
#pragma unroll
            for (int j = 0; j < 4; j++)
                acc[i][j] = __builtin_amdgcn_mfma_f32_16x16x32_bf16(af[i], bf0[j], acc[i][j], 0, 0, 0);
        __builtin_amdgcn_s_setprio(0);
        __builtin_amdgcn_s_barrier();

        // ---------- phase 1: kh=0, acc rows 4-7 ----------
#pragma unroll
        for (int i = 0; i < 4; i++) af[i] = *(const bf16x8*)&lds[cur + aRd + (i + 4) * 1024];
        if (pf) STAGEB(nxt, 0, kn);
        __builtin_amdgcn_s_barrier();
        asm volatile("s_waitcnt lgkmcnt(0)" ::: "memory");
        __builtin_amdgcn_sched_barrier(0);
        __builtin_amdgcn_s_setprio(1);
#pragma unroll
        for (int i = 0; i < 4; i++)
#pragma unroll
            for (int j = 0; j < 4; j++)
                acc[i + 4][j] = __builtin_amdgcn_mfma_f32_16x16x32_bf16(af[i], bf0[j], acc[i + 4][j], 0, 0, 0);
        __builtin_amdgcn_s_setprio(0);
        // need H2,H3 of CURRENT tile done before phase 2 reads.
        // outstanding (pf): [H2(t),H3(t),H0(t+1),H1(t+1)] = 8 -> vmcnt(4)
        if (pf) { asm volatile("s_waitcnt vmcnt(4)" ::: "memory"); }
        else    { asm volatile("s_waitcnt vmcnt(0)" ::: "memory"); }
        __builtin_amdgcn_s_barrier();

        // ---------- phase 2: kh=1, acc rows 0-3 ----------
#pragma unroll
        for (int i = 0; i < 4; i++) af[i]  = *(const bf16x8*)&lds[cur + 16384 + aRd + i * 1024];
#pragma unroll
        for (int j = 0; j < 4; j++) bf1[j] = *(const bf16x8*)&lds[cur + 16384 + bRd + j * 1024];
        if (pf) STAGEA(nxt, 1, kn + 32);
        __builtin_amdgcn_s_barrier();
        asm volatile("s_waitcnt lgkmcnt(0)" ::: "memory");
        __builtin_amdgcn_sched_barrier(0);
        __builtin_amdgcn_s_setprio(1);
#pragma unroll
        for (int i = 0; i < 4; i++)
#pragma unroll
            for (int j = 0; j < 4; j++)
                acc[i][j] = __builtin_amdgcn_mfma_f32_16x16x32_bf16(af[i], bf1[j], acc[i][j], 0, 0, 0);
        __builtin_amdgcn_s_setprio(0);
        __builtin_amdgcn_s_barrier();

        // ---------- phase 3: kh=1, acc rows 4-7 ----------
#pragma unroll
        for (int i = 0; i < 4; i++) af[i] = *(const bf16x8*)&lds[cur + 16384 + aRd + (i + 4) * 1024];
        if (pf) STAGEB(nxt, 1, kn + 32);
        __builtin_amdgcn_s_barrier();
        asm volatile("s_waitcnt lgkmcnt(0)" ::: "memory");
        __builtin_amdgcn_sched_barrier(0);
        __builtin_amdgcn_s_setprio(1);
#pragma unroll
        for (int i = 0; i < 4; i++)
#pragma unroll
            for (int j = 0; j < 4; j++)
                acc[i + 4][j] = __builtin_amdgcn_mfma_f32_16x16x32_bf16(af[i], bf1[j], acc[i + 4][j], 0, 0, 0);
        __builtin_amdgcn_s_setprio(0);
        // need H0,H1 of NEXT tile before its phase 0:
        // outstanding: [H0..H3(t+1)] = 8 -> vmcnt(4)
        if (pf) { asm volatile("s_waitcnt vmcnt(4)" ::: "memory"); }
        __builtin_amdgcn_s_barrier();
    }

#undef GLL
#undef STAGEA
#undef STAGEB

    // epilogue: C/D layout col=lane&15, row=(lane>>4)*4+reg
    const int orow = (lane >> 4) * 4;
    const int ocol = l15;

    if constexpr (CMODE == 0) {
        unsigned short* C = (unsigned short*)Cptr + (size_t)z * cStride;
#pragma unroll
        for (int mf = 0; mf < 8; mf++)
#pragma unroll
            for (int nf = 0; nf < 4; nf++) {
                const int col = rowB + wn * 64 + nf * 16 + ocol;
#pragma unroll
                for (int r = 0; r < 4; r++) {
                    const int rw = rowA + wm * 128 + mf * 16 + orow + r;
                    C[(size_t)rw * ldc + col] = f2bf(fmaxf(acc[mf][nf][r], 0.f));
                }
            }
    } else if constexpr (CMODE == 1) {
        unsigned short* C = (unsigned short*)Cptr + (size_t)z * cStride;
        const int nb = cnt[z];
        float* rs = rowsum + (size_t)z * 1024;
#pragma unroll
        for (int mf = 0; mf < 8; mf++) {
            float part[4] = {0.f, 0.f, 0.f, 0.f};
#pragma unroll
            for (int nf = 0; nf < 4; nf++) {
                const int col = rowB + wn * 64 + nf * 16 + ocol;
#pragma unroll
                for (int r = 0; r < 4; r++) {
                    float p = (col < nb) ? __expf(acc[mf][nf][r] * scale) : 0.f;
                    part[r] += p;
                    const int rw = rowA + wm * 128 + mf * 16 + orow + r;
                    C[(size_t)rw * ldc + col] = f2bf(p);
                }
            }
#pragma unroll
            for (int r = 0; r < 4; r++) {
                float s = part[r];
                s += __shfl_xor(s, 1, 64);
                s += __shfl_xor(s, 2, 64);
                s += __shfl_xor(s, 4, 64);
                s += __shfl_xor(s, 8, 64);
                if (ocol == 0)
                    atomicAdd(&rs[rowA + wm * 128 + mf * 16 + orow + r], s);
            }
        }
    } else {  // CMODE == 2
        float* C = (float*)Cptr + (size_t)z * cStride;
        const float* rs = rowsum + (size_t)z * 1024;
#pragma unroll
        for (int mf = 0; mf < 8; mf++) {
            float inv[4];
#pragma unroll
            for (int r = 0; r < 4; r++)
                inv[r] = 1.0f / rs[rowA + wm * 128 + mf * 16 + orow + r];
#pragma unroll
            for (int nf = 0; nf < 4; nf++) {
                const int col = rowB + wn * 64 + nf * 16 + ocol;
#pragma unroll
                for (int r = 0; r < 4; r++) {
                    const int rw = rowA + wm * 128 + mf * 16 + orow + r;
                    C[(size_t)rw * ldc + col] = acc[mf][nf][r] * inv[r];
                }
            }
        }
    }
}

extern "C" void kernel_launch(void* const* d_in, const int* in_sizes, int n_in,
                              void* d_out, int out_size, void* d_ws, size_t ws_size,
                              hipStream_t stream)
{
    const float* inputs = (const float*)d_in[0];   // [32,1024,512]
    const float* memory = (const float*)d_in[1];   // [32,1024,512]
    const int*   mmask  = (const int*)d_in[2];     // [32,1024]
    const float* W_in   = (const float*)d_in[3];   // [512,512]
    const float* W_mem  = (const float*)d_in[4];   // [512,512]
    float* out = (float*)d_out;                    // [32,1024,1024]

    char* ws = (char*)d_ws;
    const unsigned long long MB = 1048576ull;
    unsigned short* Wt_in  = (unsigned short*)(ws);                   // 512 KiB
    unsigned short* Wt_mem = (unsigned short*)(ws + 524288);          // 512 KiB
    unsigned short* InB16  = (unsigned short*)(ws + 1 * MB);          // 32 MiB
    unsigned short* MemG   = (unsigned short*)(ws + 33 * MB);         // 32 MiB
    unsigned short* P      = (unsigned short*)(ws + 1 * MB);          // 64 MiB (alias over InB16+MemG)
    unsigned short* MemGT  = (unsigned short*)(ws + 65 * MB);         // 32 MiB
    unsigned short* Xq     = (unsigned short*)(ws + 97 * MB);         // 32 MiB
    unsigned short* Xm     = (unsigned short*)(ws + 129 * MB);        // 32 MiB
    float*          rowsum = (float*)(ws + 161 * MB);                 // 128 KiB
    int*            kidx   = (int*)(ws + 161 * MB + 131072);          // 128 KiB
    int*            cntp   = (int*)(ws + 161 * MB + 262144);          // 128 B
    int*            padp   = (int*)(ws + 161 * MB + 262144 + 128);    // 128 B

    const float scale = 0.04419417382415922f;  // 1/sqrt(512)

    // 1. mask compaction + weight transposes
    mask_scan_kernel<<<32, 256, 0, stream>>>(mmask, kidx, cntp, padp);
    transpose_w_kernel<<<dim3(16, 16, 2), 256, 0, stream>>>(W_in, W_mem, Wt_in, Wt_mem);

    // 2. gather active memory rows -> MemG (bf16) + MemGT (bf16, transposed)
    gather_mem_kernel<<<dim3(32, 16, 32), 256, 0, stream>>>(
        memory, kidx, cntp, padp, MemG, MemGT);

    // 3. inputs -> bf16 + concat right half of out
    fuse_inputs_kernel<<<16384, 256, 0, stream>>>(
        (const float4*)inputs, (uint2*)InB16, (float4*)out);

    // zero rowsum (poisoned every launch)
    hipMemsetAsync(rowsum, 0, 32 * 1024 * sizeof(float), stream);

    // 4. projections: Xq = relu(inputs @ W_in)  [M=32768, N=512, K=512]
    gemm256<0, 0, 0, 0><<<dim3(2, 128, 1), 512, 0, stream>>>(
        InB16, Wt_in, Xq, 512, 512, 512, 0.f, nullptr, nullptr, nullptr,
        0, 0, 0, 512);
    //    Xm = relu(MemG @ W_mem)  [only active rows, early-exit on padded]
    gemm256<0, 1, 0, 0><<<dim3(2, 4, 32), 512, 0, stream>>>(
        MemG, Wt_mem, Xm, 512, 512, 512, 0.f, nullptr, padp, nullptr,
        1024ll * 512, 0, 1024ll * 512, 512);

    // 5. P = exp(Xq @ Xm^T * scale) for col<cnt, else 0; rowsum atomics
    gemm256<1, 0, 1, 0><<<dim3(4, 4, 32), 512, 0, stream>>>(
        Xq, Xm, P, 512, 512, 512, scale, cntp, padp, rowsum,
        1024ll * 512, 1024ll * 512, 1024ll * 1024, 1024);

    // 6. context = (P @ MemGT^T) / rowsum -> fp32 out[..., 0:512], K = padded[b]
    gemm256<2, 0, 0, 1><<<dim3(2, 4, 32), 512, 0, stream>>>(
        P, MemGT, out, 1024, 1024, 1024, 1.f, nullptr, padp, rowsum,
        1024ll * 1024, 512ll * 1024, 1024ll * 1024, 1024);
}

// Round 2
// 398.610 us; speedup vs baseline: 1.0986x; 1.0553x over previous
//
#include <hip/hip_runtime.h>

typedef __bf16 bf16x8 __attribute__((ext_vector_type(8)));
typedef float f32x4 __attribute__((ext_vector_type(4)));

__device__ __forceinline__ unsigned short f2bf(float f) {
    union { float f; unsigned u; } v; v.f = f;
    unsigned r = v.u + 0x7FFFu + ((v.u >> 16) & 1u);   // round-to-nearest-even
    return (unsigned short)(r >> 16);
}

// ---------------------------------------------------------------------------
// prep mega-kernel: one dispatch for all independent preprocessing.
//   blocks [0, 16384):     inputs fp32 -> bf16 + out[..., 512:1024] = inputs
//   blocks [16384, 16896): both weight transposes (fp32 [512,512] -> bf16 ^T)
//   blocks [16896, 16928): per-batch mask compaction + rowsum zeroing
// ---------------------------------------------------------------------------
__global__ __launch_bounds__(256) void prep_kernel(
    const float4* __restrict__ inputs4, uint2* __restrict__ InB16,
    float4* __restrict__ out4,
    const float* __restrict__ W0, const float* __restrict__ W1,
    unsigned short* __restrict__ D0, unsigned short* __restrict__ D1,
    const int* __restrict__ mask, int* __restrict__ kidx,
    int* __restrict__ cnt, int* __restrict__ padded,
    float4* __restrict__ rowsum4)
{
    __shared__ float tile[32][33];
    __shared__ int wsum[4];
    const int bid = blockIdx.x;
    const int t = threadIdx.x;

    if (bid < 16384) {
        // ---- fuse_inputs ----
        const int i = bid * 256 + t;            // 4194304 float4s total
        const int bq = i >> 7;
        const int d  = i & 127;
        float4 v = inputs4[i];
        out4[(size_t)bq * 256 + 128 + d] = v;
        union { unsigned short u[4]; uint2 p; } pk;
        pk.u[0] = f2bf(v.x); pk.u[1] = f2bf(v.y);
        pk.u[2] = f2bf(v.z); pk.u[3] = f2bf(v.w);
        InB16[i] = pk.p;
    } else if (bid < 16896) {
        // ---- weight transpose ----
        const int tb = bid - 16384;
        const float* src = (tb >> 8) ? W1 : W0;
        unsigned short* dst = (tb >> 8) ? D1 : D0;
        const int rem = tb & 255;
        const int s0 = (rem & 15) * 32, d0 = (rem >> 4) * 32;
        const int tr = t >> 5, tc = t & 31;
#pragma unroll
        for (int i = 0; i < 4; i++)
            tile[tr + i * 8][tc] = src[(size_t)(s0 + tr + i * 8) * 512 + d0 + tc];
        __syncthreads();
#pragma unroll
        for (int i = 0; i < 4; i++)
            dst[(size_t)(d0 + tr + i * 8) * 512 + s0 + tc] = f2bf(tile[tc][tr + i * 8]);
    } else {
        // ---- mask scan + rowsum zero ----
        const int b = bid - 16896;
        rowsum4[b * 256 + t] = float4{0.f, 0.f, 0.f, 0.f};
        const int* m = mask + b * 1024;
        int v[4]; int s = 0;
#pragma unroll
        for (int e = 0; e < 4; e++) { v[e] = (m[t * 4 + e] != 0) ? 1 : 0; s += v[e]; }
        const int lane = t & 63, wv = t >> 6;
        int x = s;
#pragma unroll
        for (int off = 1; off < 64; off <<= 1) {
            int y = __shfl_up(x, off, 64);
            if (lane >= off) x += y;
        }
        if (lane == 63) wsum[wv] = x;
        __syncthreads();
        int base = 0;
        for (int w = 0; w < wv; w++) base += wsum[w];
        int pos = base + x - s;   // exclusive prefix
#pragma unroll
        for (int e = 0; e < 4; e++)
            if (v[e]) kidx[b * 1024 + pos++] = t * 4 + e;
        if (t == 255) {
            int total = base + x;
            cnt[b] = total;
            padded[b] = (total + 127) & ~127;
        }
    }
}

// ---------------------------------------------------------------------------
// Gather active memory rows (fp32 -> bf16) + transposed copy
// ---------------------------------------------------------------------------
__global__ __launch_bounds__(256) void gather_mem_kernel(
    const float* __restrict__ memory, const int* __restrict__ kidx,
    const int* __restrict__ cnt, const int* __restrict__ padded,
    unsigned short* __restrict__ MemG, unsigned short* __restrict__ MemGT)
{
    const int b = blockIdx.z;
    const int j0 = blockIdx.x * 32, d0 = blockIdx.y * 32;
    if (j0 >= padded[b]) return;
    const int nb = cnt[b];
    __shared__ float tile[32][33];
    const float* src = memory + (size_t)b * 1024 * 512;
    const int t = threadIdx.x, tr = t >> 5, tc = t & 31;
#pragma unroll
    for (int i = 0; i < 4; i++) {
        int j = j0 + tr + i * 8;
        float v = 0.f;
        if (j < nb) v = src[(size_t)kidx[b * 1024 + j] * 512 + d0 + tc];
        tile[tr + i * 8][tc] = v;
        MemG[(size_t)b * 1024 * 512 + (size_t)j * 512 + d0 + tc] = f2bf(v);
    }
    __syncthreads();
#pragma unroll
    for (int i = 0; i < 4; i++) {
        int d = d0 + tr + i * 8;
        MemGT[(size_t)b * 512 * 1024 + (size_t)d * 1024 + j0 + tc] = f2bf(tile[tc][tr + i * 8]);
    }
}

// ---------------------------------------------------------------------------
// 256x256-tile, 8-wave, BK=64, 8-phase bf16 GEMM core  C = A @ Bt^T
//   (verified schedule from R1: st-swizzle + counted vmcnt(4) + setprio)
// CMODE 0: relu -> bf16
// CMODE 1: p = (col<nbv) ? exp(acc*scale) : 0 -> bf16; rs[row] += p (atomics)
// CMODE 2: acc / rs[row] -> fp32
// ---------------------------------------------------------------------------
template<int CMODE>
__device__ __forceinline__ void gemm_core(
    unsigned char* lds,
    const unsigned short* __restrict__ Ab, const unsigned short* __restrict__ Bb,
    void* __restrict__ Cb, float* __restrict__ rs, int nbv,
    int rowA, int rowB, int Kz, int lda, int ldb, int ldc, float scale)
{
    const int nt = Kz >> 6;                 // K-tiles of 64

    const int t = threadIdx.x;
    const int w = t >> 6;                   // wave 0..7
    const int lane = t & 63;
    const int wm = w >> 2;                  // 0..1 (M half)
    const int wn = w & 3;                   // 0..3 (N quarter)
    const int l15 = lane & 15;
    // phys 16B-slot byte offset for fragment reads (swizzled)
    const int sx = (((lane >> 4) ^ ((l15 >> 1) & 3)) << 4);

    // ---- staging: thread t covers linear LDS bytes [t*16) and [t*16+8192) of
    // each 16 KiB half-tile; source pre-swizzled so swizzled reads see logical data.
    const int r0 = t >> 2;                          // row 0..127 (and +128 for 2nd load)
    const int sl = (t & 3) ^ ((t >> 3) & 3);        // logical k-slot for this dest
    const unsigned short* aS0 = Ab + (size_t)(rowA + r0) * lda + sl * 8;
    const unsigned short* aS1 = aS0 + (size_t)128 * lda;
    const unsigned short* bS0 = Bb + (size_t)(rowB + r0) * ldb + sl * 8;
    const unsigned short* bS1 = bS0 + (size_t)128 * ldb;

    const int wofs = w * 1024;                      // wave-uniform LDS dest base
    const int aRd = (wm * 128 + l15) * 64 + sx;
    const int bRd = 32768 + (wn * 64 + l15) * 64 + sx;

    f32x4 acc[8][4];
#pragma unroll
    for (int i = 0; i < 8; i++)
#pragma unroll
        for (int j = 0; j < 4; j++) acc[i][j] = f32x4{0.f, 0.f, 0.f, 0.f};

#define GLL(SRC, DOFS) __builtin_amdgcn_global_load_lds(                        \
        (const __attribute__((address_space(1))) void*)(SRC),                   \
        (__attribute__((address_space(3))) void*)&lds[DOFS], 16, 0, 0)
#define STAGEA(BUF, KH, KEL) do {                                               \
        GLL(aS0 + (KEL), (BUF) * 65536 + (KH) * 16384 + wofs);                  \
        GLL(aS1 + (KEL), (BUF) * 65536 + (KH) * 16384 + wofs + 8192); } while (0)
#define STAGEB(BUF, KH, KEL) do {                                               \
        GLL(bS0 + (KEL), (BUF) * 65536 + 32768 + (KH) * 16384 + wofs);          \
        GLL(bS1 + (KEL), (BUF) * 65536 + 32768 + (KH) * 16384 + wofs + 8192); } while (0)

    // prologue: stage tile 0 (H0=A-klo, H1=B-klo, H2=A-khi, H3=B-khi)
    STAGEA(0, 0, 0); STAGEB(0, 0, 0); STAGEA(0, 1, 32); STAGEB(0, 1, 32);
    asm volatile("s_waitcnt vmcnt(4)" ::: "memory");   // H0,H1 of tile0 landed
    __builtin_amdgcn_s_barrier();

    for (int tt = 0; tt < nt; ++tt) {
        const int cur = (tt & 1) * 65536;
        const int nxt = (tt & 1) ^ 1;
        const bool pf = (tt + 1) < nt;
        const int kn = (tt + 1) * 64;
        bf16x8 af[4], bf0[4], bf1[4];

        // ---------- phase 0: kh=0, acc rows 0-3 ----------
#pragma unroll
        for (int i = 0; i < 4; i++) af[i]  = *(const bf16x8*)&lds[cur + aRd + i * 1024];
#pragma unroll
        for (int j = 0; j < 4; j++) bf0[j] = *(const bf16x8*)&lds[cur + bRd + j * 1024];
        if (pf) STAGEA(nxt, 0, kn);
        __builtin_amdgcn_s_barrier();
        asm volatile("s_waitcnt lgkmcnt(0)" ::: "memory");
        __builtin_amdgcn_sched_barrier(0);
        __builtin_amdgcn_s_setprio(1);
#pragma unroll
        for (int i = 0; i < 4; i++)
#pragma unroll
            for (int j = 0; j < 4; j++)
                acc[i][j] = __builtin_amdgcn_mfma_f32_16x16x32_bf16(af[i], bf0[j], acc[i][j], 0, 0, 0);
        __builtin_amdgcn_s_setprio(0);
        __builtin_amdgcn_s_barrier();

        // ---------- phase 1: kh=0, acc rows 4-7 ----------
#pragma unroll
        for (int i = 0; i < 4; i++) af[i] = *(const bf16x8*)&lds[cur + aRd + (i + 4) * 1024];
        if (pf) STAGEB(nxt, 0, kn);
        __builtin_amdgcn_s_barrier();
        asm volatile("s_waitcnt lgkmcnt(0)" ::: "memory");
        __builtin_amdgcn_sched_barrier(0);
        __builtin_amdgcn_s_setprio(1);
#pragma unroll
        for (int i = 0; i < 4; i++)
#pragma unroll
            for (int j = 0; j < 4; j++)
                acc[i + 4][j] = __builtin_amdgcn_mfma_f32_16x16x32_bf16(af[i], bf0[j], acc[i + 4][j], 0, 0, 0);
        __builtin_amdgcn_s_setprio(0);
        // need H2,H3 of CURRENT tile done before phase 2 reads.
        if (pf) { asm volatile("s_waitcnt vmcnt(4)" ::: "memory"); }
        else    { asm volatile("s_waitcnt vmcnt(0)" ::: "memory"); }
        __builtin_amdgcn_s_barrier();

        // ---------- phase 2: kh=1, acc rows 0-3 ----------
#pragma unroll
        for (int i = 0; i < 4; i++) af[i]  = *(const bf16x8*)&lds[cur + 16384 + aRd + i * 1024];
#pragma unroll
        for (int j = 0; j < 4; j++) bf1[j] = *(const bf16x8*)&lds[cur + 16384 + bRd + j * 1024];
        if (pf) STAGEA(nxt, 1, kn + 32);
        __builtin_amdgcn_s_barrier();
        asm volatile("s_waitcnt lgkmcnt(0)" ::: "memory");
        __builtin_amdgcn_sched_barrier(0);
        __builtin_amdgcn_s_setprio(1);
#pragma unroll
        for (int i = 0; i < 4; i++)
#pragma unroll
            for (int j = 0; j < 4; j++)
                acc[i][j] = __builtin_amdgcn_mfma_f32_16x16x32_bf16(af[i], bf1[j], acc[i][j], 0, 0, 0);
        __builtin_amdgcn_s_setprio(0);
        __builtin_amdgcn_s_barrier();

        // ---------- phase 3: kh=1, acc rows 4-7 ----------
#pragma unroll
        for (int i = 0; i < 4; i++) af[i] = *(const bf16x8*)&lds[cur + 16384 + aRd + (i + 4) * 1024];
        if (pf) STAGEB(nxt, 1, kn + 32);
        __builtin_amdgcn_s_barrier();
        asm volatile("s_waitcnt lgkmcnt(0)" ::: "memory");
        __builtin_amdgcn_sched_barrier(0);
        __builtin_amdgcn_s_setprio(1);
#pragma unroll
        for (int i = 0; i < 4; i++)
#pragma unroll
            for (int j = 0; j < 4; j++)
                acc[i + 4][j] = __builtin_amdgcn_mfma_f32_16x16x32_bf16(af[i], bf1[j], acc[i + 4][j], 0, 0, 0);
        __builtin_amdgcn_s_setprio(0);
        // need H0,H1 of NEXT tile before its phase 0.
        if (pf) { asm volatile("s_waitcnt vmcnt(4)" ::: "memory"); }
        __builtin_amdgcn_s_barrier();
    }

#undef GLL
#undef STAGEA
#undef STAGEB

    // epilogue: C/D layout col=lane&15, row=(lane>>4)*4+reg
    const int orow = (lane >> 4) * 4;
    const int ocol = l15;

    if constexpr (CMODE == 0) {
        unsigned short* C = (unsigned short*)Cb;
#pragma unroll
        for (int mf = 0; mf < 8; mf++)
#pragma unroll
            for (int nf = 0; nf < 4; nf++) {
                const int col = rowB + wn * 64 + nf * 16 + ocol;
#pragma unroll
                for (int r = 0; r < 4; r++) {
                    const int rw = rowA + wm * 128 + mf * 16 + orow + r;
                    C[(size_t)rw * ldc + col] = f2bf(fmaxf(acc[mf][nf][r], 0.f));
                }
            }
    } else if constexpr (CMODE == 1) {
        unsigned short* C = (unsigned short*)Cb;
#pragma unroll
        for (int mf = 0; mf < 8; mf++) {
            float part[4] = {0.f, 0.f, 0.f, 0.f};
#pragma unroll
            for (int nf = 0; nf < 4; nf++) {
                const int col = rowB + wn * 64 + nf * 16 + ocol;
#pragma unroll
                for (int r = 0; r < 4; r++) {
                    float p = (col < nbv) ? __expf(acc[mf][nf][r] * scale) : 0.f;
                    part[r] += p;
                    const int rw = rowA + wm * 128 + mf * 16 + orow + r;
                    C[(size_t)rw * ldc + col] = f2bf(p);
                }
            }
#pragma unroll
            for (int r = 0; r < 4; r++) {
                float s = part[r];
                s += __shfl_xor(s, 1, 64);
                s += __shfl_xor(s, 2, 64);
                s += __shfl_xor(s, 4, 64);
                s += __shfl_xor(s, 8, 64);
                if (ocol == 0)
                    atomicAdd(&rs[rowA + wm * 128 + mf * 16 + orow + r], s);
            }
        }
    } else {  // CMODE == 2
        float* C = (float*)Cb;
#pragma unroll
        for (int mf = 0; mf < 8; mf++) {
            float inv[4];
#pragma unroll
            for (int r = 0; r < 4; r++)
                inv[r] = 1.0f / rs[rowA + wm * 128 + mf * 16 + orow + r];
#pragma unroll
            for (int nf = 0; nf < 4; nf++) {
                const int col = rowB + wn * 64 + nf * 16 + ocol;
#pragma unroll
                for (int r = 0; r < 4; r++) {
                    const int rw = rowA + wm * 128 + mf * 16 + orow + r;
                    C[(size_t)rw * ldc + col] = acc[mf][nf][r] * inv[r];
                }
            }
        }
    }
}

// ---------------------------------------------------------------------------
// Merged projection GEMMs: y<128 -> Xq = relu(InB16 @ Wt_in^T)
//                          y>=128 -> Xm = relu(MemG @ Wt_mem^T), per-batch
// ---------------------------------------------------------------------------
__global__ __launch_bounds__(512, 2) void gemm_proj_kernel(
    const unsigned short* __restrict__ InB16, const unsigned short* __restrict__ WtIn,
    unsigned short* __restrict__ Xq,
    const unsigned short* __restrict__ MemG, const unsigned short* __restrict__ WtMem,
    unsigned short* __restrict__ Xm, const int* __restrict__ padded)
{
    __shared__ __align__(16) unsigned char lds[131072];
    const int y = blockIdx.y;
    const int rowB = blockIdx.x * 256;
    const unsigned short* A;
    const unsigned short* Bt;
    unsigned short* C;
    int rowA;
    if (y < 128) {
        A = InB16; Bt = WtIn; C = Xq; rowA = y * 256;
    } else {
        const int idx = y - 128;
        const int z = idx >> 2;
        rowA = (idx & 3) * 256;
        if (rowA >= padded[z]) return;
        A = MemG + (size_t)z * 524288;
        Bt = WtMem;
        C = Xm + (size_t)z * 524288;
    }
    gemm_core<0>(lds, A, Bt, (void*)C, nullptr, 0, rowA, rowB,
                 512, 512, 512, 512, 0.f);
}

// P = exp(Xq @ Xm^T * scale) masked; rowsum atomics
__global__ __launch_bounds__(512, 2) void gemm_p_kernel(
    const unsigned short* __restrict__ Xq, const unsigned short* __restrict__ Xm,
    unsigned short* __restrict__ P, const int* __restrict__ cnt,
    const int* __restrict__ padded, float* __restrict__ rowsum, float scale)
{
    __shared__ __align__(16) unsigned char lds[131072];
    const int z = blockIdx.z;
    const int rowB = blockIdx.x * 256;
    if (rowB >= padded[z]) return;
    gemm_core<1>(lds, Xq + (size_t)z * 524288, Xm + (size_t)z * 524288,
                 (void*)(P + (size_t)z * 1048576), rowsum + (size_t)z * 1024, cnt[z],
                 blockIdx.y * 256, rowB, 512, 512, 512, 1024, scale);
}

// context = (P @ MemGT^T) / rowsum -> fp32 out[..., 0:512]
__global__ __launch_bounds__(512, 2) void gemm_ctx_kernel(
    const unsigned short* __restrict__ P, const unsigned short* __restrict__ MemGT,
    float* __restrict__ out, const int* __restrict__ padded, float* __restrict__ rowsum)
{
    __shared__ __align__(16) unsigned char lds[131072];
    const int z = blockIdx.z;
    gemm_core<2>(lds, P + (size_t)z * 1048576, MemGT + (size_t)z * 524288,
                 (void*)(out + (size_t)z * 1048576), rowsum + (size_t)z * 1024, 0,
                 blockIdx.y * 256, blockIdx.x * 256, padded[z],
                 1024, 1024, 1024, 1.f);
}

extern "C" void kernel_launch(void* const* d_in, const int* in_sizes, int n_in,
                              void* d_out, int out_size, void* d_ws, size_t ws_size,
                              hipStream_t stream)
{
    const float* inputs = (const float*)d_in[0];   // [32,1024,512]
    const float* memory = (const float*)d_in[1];   // [32,1024,512]
    const int*   mmask  = (const int*)d_in[2];     // [32,1024]
    const float* W_in   = (const float*)d_in[3];   // [512,512]
    const float* W_mem  = (const float*)d_in[4];   // [512,512]
    float* out = (float*)d_out;                    // [32,1024,1024]

    char* ws = (char*)d_ws;
    const unsigned long long MB = 1048576ull;
    unsigned short* Wt_in  = (unsigned short*)(ws);                   // 512 KiB
    unsigned short* Wt_mem = (unsigned short*)(ws + 524288);          // 512 KiB
    unsigned short* InB16  = (unsigned short*)(ws + 1 * MB);          // 32 MiB
    unsigned short* MemG   = (unsigned short*)(ws + 33 * MB);         // 32 MiB
    unsigned short* P      = (unsigned short*)(ws + 1 * MB);          // 64 MiB (alias over InB16+MemG)
    unsigned short* MemGT  = (unsigned short*)(ws + 65 * MB);         // 32 MiB
    unsigned short* Xq     = (unsigned short*)(ws + 97 * MB);         // 32 MiB
    unsigned short* Xm     = (unsigned short*)(ws + 129 * MB);        // 32 MiB
    float*          rowsum = (float*)(ws + 161 * MB);                 // 128 KiB
    int*            kidx   = (int*)(ws + 161 * MB + 131072);          // 128 KiB
    int*            cntp   = (int*)(ws + 161 * MB + 262144);          // 128 B
    int*            padp   = (int*)(ws + 161 * MB + 262144 + 128);    // 128 B

    const float scale = 0.04419417382415922f;  // 1/sqrt(512)

    // 1. all independent prep in one dispatch (cast+concat, transposes, scan, rowsum=0)
    prep_kernel<<<16928, 256, 0, stream>>>(
        (const float4*)inputs, (uint2*)InB16, (float4*)out,
        W_in, W_mem, Wt_in, Wt_mem,
        mmask, kidx, cntp, padp, (float4*)rowsum);

    // 2. gather active memory rows -> MemG (bf16) + MemGT (bf16, transposed)
    gather_mem_kernel<<<dim3(32, 16, 32), 256, 0, stream>>>(
        memory, kidx, cntp, padp, MemG, MemGT);

    // 3. both projections in one dispatch (512 blocks = 2/CU)
    gemm_proj_kernel<<<dim3(2, 256, 1), 512, 0, stream>>>(
        InB16, Wt_in, Xq, MemG, Wt_mem, Xm, padp);

    // 4. P = exp(Xq @ Xm^T * scale) for col<cnt, else 0; rowsum atomics
    gemm_p_kernel<<<dim3(4, 4, 32), 512, 0, stream>>>(
        Xq, Xm, P, cntp, padp, rowsum, scale);

    // 5. context = (P @ MemGT^T) / rowsum -> fp32 out[..., 0:512], K = padded[b]
    gemm_ctx_kernel<<<dim3(2, 4, 32), 512, 0, stream>>>(
        P, MemGT, out, padp, rowsum);
}

// Round 3
// 376.547 us; speedup vs baseline: 1.1629x; 1.0586x over previous
//
#include <hip/hip_runtime.h>

typedef __bf16 bf16x8 __attribute__((ext_vector_type(8)));
typedef float f32x4 __attribute__((ext_vector_type(4)));

__device__ __forceinline__ unsigned short f2bf(float f) {
    union { float f; unsigned u; } v; v.f = f;
    unsigned r = v.u + 0x7FFFu + ((v.u >> 16) & 1u);   // round-to-nearest-even
    return (unsigned short)(r >> 16);
}

// ---------------------------------------------------------------------------
// prep mega-kernel: ALL preprocessing in one dispatch.
//   blocks [0, 1024):       gather active memory rows -> MemG + MemGT
//                           (local mask scan; b = bid>>5, jt = bid&31)
//   blocks [1024, 1056):    per-batch mask scan -> cnt/padded + rowsum zero
//   blocks [1056, 1568):    both weight transposes (fp32 [512,512] -> bf16 ^T)
//   blocks [1568, 17952):   inputs fp32 -> bf16 + out[..., 512:1024] = inputs
// ---------------------------------------------------------------------------
__global__ __launch_bounds__(256) void prep_kernel(
    const float4* __restrict__ inputs4, uint2* __restrict__ InB16,
    float4* __restrict__ out4,
    const float* __restrict__ W0, const float* __restrict__ W1,
    unsigned short* __restrict__ D0, unsigned short* __restrict__ D1,
    const int* __restrict__ mask,
    int* __restrict__ cnt, int* __restrict__ padded,
    float4* __restrict__ rowsum4,
    const float* __restrict__ memory,
    unsigned short* __restrict__ MemG, unsigned short* __restrict__ MemGT)
{
    __shared__ float tile[32][33];
    __shared__ int wsum[4];
    __shared__ int kidx32[32];
    const int bid = blockIdx.x;
    const int t = threadIdx.x;

    if (bid < 1024) {
        // ---- gather (with local mask scan) ----
        const int b = bid >> 5;          // batch
        const int jt = bid & 31;         // j-tile (32 rows)
        const int* m = mask + b * 1024;
        int v[4]; int s = 0;
#pragma unroll
        for (int e = 0; e < 4; e++) { v[e] = (m[t * 4 + e] != 0) ? 1 : 0; s += v[e]; }
        const int lane = t & 63, wv = t >> 6;
        int x = s;
#pragma unroll
        for (int off = 1; off < 64; off <<= 1) {
            int y = __shfl_up(x, off, 64);
            if (lane >= off) x += y;
        }
        if (lane == 63) wsum[wv] = x;
        __syncthreads();
        int base = 0;
        for (int w = 0; w < wv; w++) base += wsum[w];
        const int nb = wsum[0] + wsum[1] + wsum[2] + wsum[3];
        const int pb = (nb + 127) & ~127;
        const int j0 = jt * 32;
        if (j0 >= pb) return;            // block-uniform
        int pos = base + x - s;          // exclusive prefix
#pragma unroll
        for (int e = 0; e < 4; e++)
            if (v[e]) {
                int p = pos++;
                if (p >= j0 && p < j0 + 32) kidx32[p - j0] = t * 4 + e;
            }
        __syncthreads();

        const float* src = memory + (size_t)b * 1024 * 512;
        const int tr = t >> 5, tc = t & 31;
        for (int d0 = 0; d0 < 512; d0 += 32) {
#pragma unroll
            for (int i = 0; i < 4; i++) {
                const int jj = tr + i * 8;
                const int j = j0 + jj;
                float vv = 0.f;
                if (j < nb) vv = src[(size_t)kidx32[jj] * 512 + d0 + tc];
                tile[jj][tc] = vv;
                MemG[(size_t)b * 1024 * 512 + (size_t)j * 512 + d0 + tc] = f2bf(vv);
            }
            __syncthreads();
#pragma unroll
            for (int i = 0; i < 4; i++) {
                const int d = d0 + tr + i * 8;
                MemGT[(size_t)b * 512 * 1024 + (size_t)d * 1024 + j0 + tc] =
                    f2bf(tile[tc][tr + i * 8]);
            }
            __syncthreads();
        }
    } else if (bid < 1056) {
        // ---- mask scan -> cnt/padded + rowsum zero ----
        const int b = bid - 1024;
        rowsum4[b * 256 + t] = float4{0.f, 0.f, 0.f, 0.f};
        const int* m = mask + b * 1024;
        int s = 0;
#pragma unroll
        for (int e = 0; e < 4; e++) s += (m[t * 4 + e] != 0) ? 1 : 0;
        const int lane = t & 63, wv = t >> 6;
        int x = s;
#pragma unroll
        for (int off = 1; off < 64; off <<= 1) {
            int y = __shfl_up(x, off, 64);
            if (lane >= off) x += y;
        }
        if (lane == 63) wsum[wv] = x;
        __syncthreads();
        if (t == 255) {
            int total = wsum[0] + wsum[1] + wsum[2] + wsum[3];
            cnt[b] = total;
            padded[b] = (total + 127) & ~127;
        }
    } else if (bid < 1568) {
        // ---- weight transpose ----
        const int tb = bid - 1056;
        const float* src = (tb >> 8) ? W1 : W0;
        unsigned short* dst = (tb >> 8) ? D1 : D0;
        const int rem = tb & 255;
        const int s0 = (rem & 15) * 32, d0 = (rem >> 4) * 32;
        const int tr = t >> 5, tc = t & 31;
#pragma unroll
        for (int i = 0; i < 4; i++)
            tile[tr + i * 8][tc] = src[(size_t)(s0 + tr + i * 8) * 512 + d0 + tc];
        __syncthreads();
#pragma unroll
        for (int i = 0; i < 4; i++)
            dst[(size_t)(d0 + tr + i * 8) * 512 + s0 + tc] = f2bf(tile[tc][tr + i * 8]);
    } else {
        // ---- fuse_inputs ----
        const int i = (bid - 1568) * 256 + t;   // 4194304 float4s total
        const int bq = i >> 7;
        const int d  = i & 127;
        float4 v = inputs4[i];
        out4[(size_t)bq * 256 + 128 + d] = v;
        union { unsigned short u[4]; uint2 p; } pk;
        pk.u[0] = f2bf(v.x); pk.u[1] = f2bf(v.y);
        pk.u[2] = f2bf(v.z); pk.u[3] = f2bf(v.w);
        InB16[i] = pk.p;
    }
}

// ---------------------------------------------------------------------------
// 256x256-tile, 8-wave, BK=64, 8-phase bf16 GEMM core  C = A @ Bt^T
//   (verified schedule: st-swizzle + counted vmcnt(4) + setprio)
// CMODE 0: relu -> bf16
// CMODE 1: p = (col<nbv) ? exp(acc*scale) : 0 -> bf16; rs[row] += p (atomics)
// CMODE 2: acc / rs[row] -> fp32
// ---------------------------------------------------------------------------
template<int CMODE>
__device__ __forceinline__ void gemm_core(
    unsigned char* lds,
    const unsigned short* __restrict__ Ab, const unsigned short* __restrict__ Bb,
    void* __restrict__ Cb, float* __restrict__ rs, int nbv,
    int rowA, int rowB, int Kz, int lda, int ldb, int ldc, float scale)
{
    const int nt = Kz >> 6;                 // K-tiles of 64

    const int t = threadIdx.x;
    const int w = t >> 6;                   // wave 0..7
    const int lane = t & 63;
    const int wm = w >> 2;                  // 0..1 (M half)
    const int wn = w & 3;                   // 0..3 (N quarter)
    const int l15 = lane & 15;
    // phys 16B-slot byte offset for fragment reads (swizzled)
    const int sx = (((lane >> 4) ^ ((l15 >> 1) & 3)) << 4);

    // ---- staging: thread t covers linear LDS bytes [t*16) and [t*16+8192) of
    // each 16 KiB half-tile; source pre-swizzled so swizzled reads see logical data.
    const int r0 = t >> 2;                          // row 0..127 (and +128 for 2nd load)
    const int sl = (t & 3) ^ ((t >> 3) & 3);        // logical k-slot for this dest
    const unsigned short* aS0 = Ab + (size_t)(rowA + r0) * lda + sl * 8;
    const unsigned short* aS1 = aS0 + (size_t)128 * lda;
    const unsigned short* bS0 = Bb + (size_t)(rowB + r0) * ldb + sl * 8;
    const unsigned short* bS1 = bS0 + (size_t)128 * ldb;

    const int wofs = w * 1024;                      // wave-uniform LDS dest base
    const int aRd = (wm * 128 + l15) * 64 + sx;
    const int bRd = 32768 + (wn * 64 + l15) * 64 + sx;

    f32x4 acc[8][4];
#pragma unroll
    for (int i = 0; i < 8; i++)
#pragma unroll
        for (int j = 0; j < 4; j++) acc[i][j] = f32x4{0.f, 0.f, 0.f, 0.f};

#define GLL(SRC, DOFS) __builtin_amdgcn_global_load_lds(                        \
        (const __attribute__((address_space(1))) void*)(SRC),                   \
        (__attribute__((address_space(3))) void*)&lds[DOFS], 16, 0, 0)
#define STAGEA(BUF, KH, KEL) do {                                               \
        GLL(aS0 + (KEL), (BUF) * 65536 + (KH) * 16384 + wofs);                  \
        GLL(aS1 + (KEL), (BUF) * 65536 + (KH) * 16384 + wofs + 8192); } while (0)
#define STAGEB(BUF, KH, KEL) do {                                               \
        GLL(bS0 + (KEL), (BUF) * 65536 + 32768 + (KH) * 16384 + wofs);          \
        GLL(bS1 + (KEL), (BUF) * 65536 + 32768 + (KH) * 16384 + wofs + 8192); } while (0)

    // prologue: stage tile 0 (H0=A-klo, H1=B-klo, H2=A-khi, H3=B-khi)
    STAGEA(0, 0, 0); STAGEB(0, 0, 0); STAGEA(0, 1, 32); STAGEB(0, 1, 32);
    asm volatile("s_waitcnt vmcnt(4)" ::: "memory");   // H0,H1 of tile0 landed
    __builtin_amdgcn_s_barrier();

    for (int tt = 0; tt < nt; ++tt) {
        const int cur = (tt & 1) * 65536;
        const int nxt = (tt & 1) ^ 1;
        const bool pf = (tt + 1) < nt;
        const int kn = (tt + 1) * 64;
        bf16x8 af[4], bf0[4], bf1[4];

        // ---------- phase 0: kh=0, acc rows 0-3 ----------
#pragma unroll
        for (int i = 0; i < 4; i++) af[i]  = *(const bf16x8*)&lds[cur + aRd + i * 1024];
#pragma unroll
        for (int j = 0; j < 4; j++) bf0[j] = *(const bf16x8*)&lds[cur + bRd + j * 1024];
        if (pf) STAGEA(nxt, 0, kn);
        __builtin_amdgcn_s_barrier();
        asm volatile("s_waitcnt lgkmcnt(0)" ::: "memory");
        __builtin_amdgcn_sched_barrier(0);
        __builtin_amdgcn_s_setprio(1);
#pragma unroll
        for (int i = 0; i < 4; i++)
#pragma unroll
            for (int j = 0; j < 4; j++)
                acc[i][j] = __builtin_amdgcn_mfma_f32_16x16x32_bf16(af[i], bf0[j], acc[i][j], 0, 0, 0);
        __builtin_amdgcn_s_setprio(0);
        __builtin_amdgcn_s_barrier();

        // ---------- phase 1: kh=0, acc rows 4-7 ----------
#pragma unroll
        for (int i = 0; i < 4; i++) af[i] = *(const bf16x8*)&lds[cur + aRd + (i + 4) * 1024];
        if (pf) STAGEB(nxt, 0, kn);
        __builtin_amdgcn_s_barrier();
        asm volatile("s_waitcnt lgkmcnt(0)" ::: "memory");
        __builtin_amdgcn_sched_barrier(0);
        __builtin_amdgcn_s_setprio(1);
#pragma unroll
        for (int i = 0; i < 4; i++)
#pragma unroll
            for (int j = 0; j < 4; j++)
                acc[i + 4][j] = __builtin_amdgcn_mfma_f32_16x16x32_bf16(af[i], bf0[j], acc[i + 4][j], 0, 0, 0);
        __builtin_amdgcn_s_setprio(0);
        // need H2,H3 of CURRENT tile done before phase 2 reads.
        if (pf) { asm volatile("s_waitcnt vmcnt(4)" ::: "memory"); }
        else    { asm volatile("s_waitcnt vmcnt(0)" ::: "memory"); }
        __builtin_amdgcn_s_barrier();

        // ---------- phase 2: kh=1, acc rows 0-3 ----------
#pragma unroll
        for (int i = 0; i < 4; i++) af[i]  = *(const bf16x8*)&lds[cur + 16384 + aRd + i * 1024];
#pragma unroll
        for (int j = 0; j < 4; j++) bf1[j] = *(const bf16x8*)&lds[cur + 16384 + bRd + j * 1024];
        if (pf) STAGEA(nxt, 1, kn + 32);
        __builtin_amdgcn_s_barrier();
        asm volatile("s_waitcnt lgkmcnt(0)" ::: "memory");
        __builtin_amdgcn_sched_barrier(0);
        __builtin_amdgcn_s_setprio(1);
#pragma unroll
        for (int i = 0; i < 4; i++)
#pragma unroll
            for (int j = 0; j < 4; j++)
                acc[i][j] = __builtin_amdgcn_mfma_f32_16x16x32_bf16(af[i], bf1[j], acc[i][j], 0, 0, 0);
        __builtin_amdgcn_s_setprio(0);
        __builtin_amdgcn_s_barrier();

        // ---------- phase 3: kh=1, acc rows 4-7 ----------
#pragma unroll
        for (int i = 0; i < 4; i++) af[i] = *(const bf16x8*)&lds[cur + 16384 + aRd + (i + 4) * 1024];
        if (pf) STAGEB(nxt, 1, kn + 32);
        __builtin_amdgcn_s_barrier();
        asm volatile("s_waitcnt lgkmcnt(0)" ::: "memory");
        __builtin_amdgcn_sched_barrier(0);
        __builtin_amdgcn_s_setprio(1);
#pragma unroll
        for (int i = 0; i < 4; i++)
#pragma unroll
            for (int j = 0; j < 4; j++)
                acc[i + 4][j] = __builtin_amdgcn_mfma_f32_16x16x32_bf16(af[i], bf1[j], acc[i + 4][j], 0, 0, 0);
        __builtin_amdgcn_s_setprio(0);
        // need H0,H1 of NEXT tile before its phase 0.
        if (pf) { asm volatile("s_waitcnt vmcnt(4)" ::: "memory"); }
        __builtin_amdgcn_s_barrier();
    }

#undef GLL
#undef STAGEA
#undef STAGEB

    // epilogue: C/D layout col=lane&15, row=(lane>>4)*4+reg
    const int orow = (lane >> 4) * 4;
    const int ocol = l15;

    if constexpr (CMODE == 0) {
        unsigned short* C = (unsigned short*)Cb;
#pragma unroll
        for (int mf = 0; mf < 8; mf++)
#pragma unroll
            for (int nf = 0; nf < 4; nf++) {
                const int col = rowB + wn * 64 + nf * 16 + ocol;
#pragma unroll
                for (int r = 0; r < 4; r++) {
                    const int rw = rowA + wm * 128 + mf * 16 + orow + r;
                    C[(size_t)rw * ldc + col] = f2bf(fmaxf(acc[mf][nf][r], 0.f));
                }
            }
    } else if constexpr (CMODE == 1) {
        unsigned short* C = (unsigned short*)Cb;
#pragma unroll
        for (int mf = 0; mf < 8; mf++) {
            float part[4] = {0.f, 0.f, 0.f, 0.f};
#pragma unroll
            for (int nf = 0; nf < 4; nf++) {
                const int col = rowB + wn * 64 + nf * 16 + ocol;
#pragma unroll
                for (int r = 0; r < 4; r++) {
                    float p = (col < nbv) ? __expf(acc[mf][nf][r] * scale) : 0.f;
                    part[r] += p;
                    const int rw = rowA + wm * 128 + mf * 16 + orow + r;
                    C[(size_t)rw * ldc + col] = f2bf(p);
                }
            }
#pragma unroll
            for (int r = 0; r < 4; r++) {
                float s = part[r];
                s += __shfl_xor(s, 1, 64);
                s += __shfl_xor(s, 2, 64);
                s += __shfl_xor(s, 4, 64);
                s += __shfl_xor(s, 8, 64);
                if (ocol == 0)
                    atomicAdd(&rs[rowA + wm * 128 + mf * 16 + orow + r], s);
            }
        }
    } else {  // CMODE == 2
        float* C = (float*)Cb;
#pragma unroll
        for (int mf = 0; mf < 8; mf++) {
            float inv[4];
#pragma unroll
            for (int r = 0; r < 4; r++)
                inv[r] = 1.0f / rs[rowA + wm * 128 + mf * 16 + orow + r];
#pragma unroll
            for (int nf = 0; nf < 4; nf++) {
                const int col = rowB + wn * 64 + nf * 16 + ocol;
#pragma unroll
                for (int r = 0; r < 4; r++) {
                    const int rw = rowA + wm * 128 + mf * 16 + orow + r;
                    C[(size_t)rw * ldc + col] = acc[mf][nf][r] * inv[r];
                }
            }
        }
    }
}

// ---------------------------------------------------------------------------
// Merged projection GEMMs (1-D grid of 512, XCD-swizzled so the two rowB
// halves of one A-stripe share an XCD/L2):
//   y<128 -> Xq = relu(InB16 @ Wt_in^T);  y>=128 -> Xm = relu(MemG @ Wt_mem^T)
// ---------------------------------------------------------------------------
__global__ __launch_bounds__(512, 2) void gemm_proj_kernel(
    const unsigned short* __restrict__ InB16, const unsigned short* __restrict__ WtIn,
    unsigned short* __restrict__ Xq,
    const unsigned short* __restrict__ MemG, const unsigned short* __restrict__ WtMem,
    unsigned short* __restrict__ Xm, const int* __restrict__ padded)
{
    __shared__ __align__(16) unsigned char lds[131072];
    const int id = blockIdx.x;
    const int xcd = id & 7, slot = id >> 3;
    const int y = xcd + 8 * (slot >> 1);    // 0..255, both x-halves same XCD
    const int x = slot & 1;
    const int rowB = x * 256;
    const unsigned short* A;
    const unsigned short* Bt;
    unsigned short* C;
    int rowA;
    if (y < 128) {
        A = InB16; Bt = WtIn; C = Xq; rowA = y * 256;
    } else {
        const int idx = y - 128;
        const int z = idx >> 2;
        rowA = (idx & 3) * 256;
        if (rowA >= padded[z]) return;
        A = MemG + (size_t)z * 524288;
        Bt = WtMem;
        C = Xm + (size_t)z * 524288;
    }
    gemm_core<0>(lds, A, Bt, (void*)C, nullptr, 0, rowA, rowB,
                 512, 512, 512, 512, 0.f);
}

// P = exp(Xq @ Xm^T * scale) masked; rowsum atomics.
// 1-D grid 512, XCD-swizzled: all 16 blocks of a batch on one XCD.
__global__ __launch_bounds__(512, 2) void gemm_p_kernel(
    const unsigned short* __restrict__ Xq, const unsigned short* __restrict__ Xm,
    unsigned short* __restrict__ P, const int* __restrict__ cnt,
    const int* __restrict__ padded, float* __restrict__ rowsum, float scale)
{
    __shared__ __align__(16) unsigned char lds[131072];
    const int id = blockIdx.x;
    const int xcd = id & 7, slot = id >> 3;
    const int z = xcd + 8 * (slot >> 4);    // 4 batches per XCD, 16 blocks each
    const int r = slot & 15;
    const int x = r & 3, y = r >> 2;
    const int rowB = x * 256;
    if (rowB >= padded[z]) return;
    gemm_core<1>(lds, Xq + (size_t)z * 524288, Xm + (size_t)z * 524288,
                 (void*)(P + (size_t)z * 1048576), rowsum + (size_t)z * 1024, cnt[z],
                 y * 256, rowB, 512, 512, 512, 1024, scale);
}

// context = (P @ MemGT^T) / rowsum -> fp32 out[..., 0:512]
// 1-D grid 256, XCD-swizzled: all 8 blocks of a batch on one XCD.
__global__ __launch_bounds__(512, 2) void gemm_ctx_kernel(
    const unsigned short* __restrict__ P, const unsigned short* __restrict__ MemGT,
    float* __restrict__ out, const int* __restrict__ padded, float* __restrict__ rowsum)
{
    __shared__ __align__(16) unsigned char lds[131072];
    const int id = blockIdx.x;
    const int xcd = id & 7, slot = id >> 3;
    const int z = xcd + 8 * (slot >> 3);    // 4 batches per XCD, 8 blocks each
    const int r = slot & 7;
    const int x = r & 1, y = r >> 1;
    gemm_core<2>(lds, P + (size_t)z * 1048576, MemGT + (size_t)z * 524288,
                 (void*)(out + (size_t)z * 1048576), rowsum + (size_t)z * 1024, 0,
                 y * 256, x * 256, padded[z],
                 1024, 1024, 1024, 1.f);
}

extern "C" void kernel_launch(void* const* d_in, const int* in_sizes, int n_in,
                              void* d_out, int out_size, void* d_ws, size_t ws_size,
                              hipStream_t stream)
{
    const float* inputs = (const float*)d_in[0];   // [32,1024,512]
    const float* memory = (const float*)d_in[1];   // [32,1024,512]
    const int*   mmask  = (const int*)d_in[2];     // [32,1024]
    const float* W_in   = (const float*)d_in[3];   // [512,512]
    const float* W_mem  = (const float*)d_in[4];   // [512,512]
    float* out = (float*)d_out;                    // [32,1024,1024]

    char* ws = (char*)d_ws;
    const unsigned long long MB = 1048576ull;
    unsigned short* Wt_in  = (unsigned short*)(ws);                   // 512 KiB
    unsigned short* Wt_mem = (unsigned short*)(ws + 524288);          // 512 KiB
    unsigned short* InB16  = (unsigned short*)(ws + 1 * MB);          // 32 MiB
    unsigned short* MemG   = (unsigned short*)(ws + 33 * MB);         // 32 MiB
    unsigned short* P      = (unsigned short*)(ws + 1 * MB);          // 64 MiB (alias over InB16+MemG)
    unsigned short* MemGT  = (unsigned short*)(ws + 65 * MB);         // 32 MiB
    unsigned short* Xq     = (unsigned short*)(ws + 97 * MB);         // 32 MiB
    unsigned short* Xm     = (unsigned short*)(ws + 129 * MB);        // 32 MiB
    float*          rowsum = (float*)(ws + 161 * MB);                 // 128 KiB
    int*            cntp   = (int*)(ws + 161 * MB + 262144);          // 128 B
    int*            padp   = (int*)(ws + 161 * MB + 262144 + 128);    // 128 B

    const float scale = 0.04419417382415922f;  // 1/sqrt(512)

    // 1. everything independent in one dispatch:
    //    gather (local scan) + scan/rowsum + transposes + cast/concat
    prep_kernel<<<17952, 256, 0, stream>>>(
        (const float4*)inputs, (uint2*)InB16, (float4*)out,
        W_in, W_mem, Wt_in, Wt_mem,
        mmask, cntp, padp, (float4*)rowsum,
        memory, MemG, MemGT);

    // 2. both projections, XCD-swizzled
    gemm_proj_kernel<<<512, 512, 0, stream>>>(
        InB16, Wt_in, Xq, MemG, Wt_mem, Xm, padp);

    // 3. P = exp(Xq @ Xm^T * scale) for col<cnt, else 0; rowsum atomics
    gemm_p_kernel<<<512, 512, 0, stream>>>(
        Xq, Xm, P, cntp, padp, rowsum, scale);

    // 4. context = (P @ MemGT^T) / rowsum -> fp32 out[..., 0:512]
    gemm_ctx_kernel<<<256, 512, 0, stream>>>(
        P, MemGT, out, padp, rowsum);
}

// Round 4
// 363.383 us; speedup vs baseline: 1.2050x; 1.0362x over previous
//
#include <hip/hip_runtime.h>

typedef __bf16 bf16x8 __attribute__((ext_vector_type(8)));
typedef float f32x4 __attribute__((ext_vector_type(4)));

__device__ __forceinline__ unsigned short f2bf(float f) {
    union { float f; unsigned u; } v; v.f = f;
    unsigned r = v.u + 0x7FFFu + ((v.u >> 16) & 1u);   // round-to-nearest-even
    return (unsigned short)(r >> 16);
}

// ---------------------------------------------------------------------------
// prep mega-kernel: ALL preprocessing in one dispatch.
//   blocks [0, 1024):       gather active memory rows -> MemG + MemGT
//                           (local mask scan; b = bid>>5, jt = bid&31)
//   blocks [1024, 1056):    per-batch mask scan -> cnt/padded + rowsum zero
//   blocks [1056, 1568):    both weight transposes (fp32 [512,512] -> bf16 ^T)
//   blocks [1568, 17952):   inputs fp32 -> bf16 + out[..., 512:1024] = inputs
// ---------------------------------------------------------------------------
__global__ __launch_bounds__(256) void prep_kernel(
    const float4* __restrict__ inputs4, uint2* __restrict__ InB16,
    float4* __restrict__ out4,
    const float* __restrict__ W0, const float* __restrict__ W1,
    unsigned short* __restrict__ D0, unsigned short* __restrict__ D1,
    const int* __restrict__ mask,
    int* __restrict__ cnt, int* __restrict__ padded,
    float4* __restrict__ rowsum4,
    const float* __restrict__ memory,
    unsigned short* __restrict__ MemG, unsigned short* __restrict__ MemGT)
{
    __shared__ float tile[32][33];
    __shared__ float tileG[32][132];
    __shared__ int wsum[4];
    __shared__ int kidx32[32];
    const int bid = blockIdx.x;
    const int t = threadIdx.x;

    if (bid < 1024) {
        // ---- gather (with local mask scan), deep-ILP version ----
        const int b = bid >> 5;          // batch
        const int jt = bid & 31;         // j-tile (32 rows)
        const int j0 = jt * 32;
        const int* m = mask + b * 1024;
        int v[4]; int s = 0;
#pragma unroll
        for (int e = 0; e < 4; e++) { v[e] = (m[t * 4 + e] != 0) ? 1 : 0; s += v[e]; }
        const int lane = t & 63, wv = t >> 6;
        int x = s;
#pragma unroll
        for (int off = 1; off < 64; off <<= 1) {
            int y = __shfl_up(x, off, 64);
            if (lane >= off) x += y;
        }
        if (lane == 63) wsum[wv] = x;
        __syncthreads();
        int base = 0;
        for (int w = 0; w < wv; w++) base += wsum[w];
        const int nb = wsum[0] + wsum[1] + wsum[2] + wsum[3];
        const int pb = (nb + 127) & ~127;
        if (j0 >= pb) return;            // block-uniform
        int pos = base + x - s;          // exclusive prefix
#pragma unroll
        for (int e = 0; e < 4; e++)
            if (v[e]) {
                int p = pos++;
                if (p >= j0 && p < j0 + 32) kidx32[p - j0] = t * 4 + e;
            }
        __syncthreads();

        const float4* src4 = (const float4*)(memory + (size_t)b * 1024 * 512);
        const int jj = t >> 3;           // 0..31 (row within tile)
        const int cq = t & 7;            // 0..7  (16-float column chunk)
        const bool live = (j0 + jj) < nb;
        const int krow = live ? kidx32[jj] : 0;

        // issue ALL global reads up front (16 float4 = 64 regs, 1 latency exposure)
        float4 vv[4][4];
        if (live) {
            const float4* rp = src4 + (size_t)krow * 128 + cq * 4;
#pragma unroll
            for (int c = 0; c < 4; c++)
#pragma unroll
                for (int i = 0; i < 4; i++) vv[c][i] = rp[c * 32 + i];
        } else {
#pragma unroll
            for (int c = 0; c < 4; c++)
#pragma unroll
                for (int i = 0; i < 4; i++) vv[c][i] = float4{0.f, 0.f, 0.f, 0.f};
        }

        // MemG: 32 B contiguous per thread per chunk
        unsigned short* mg = MemG + (size_t)b * 1024 * 512 + (size_t)(j0 + jj) * 512;
#pragma unroll
        for (int c = 0; c < 4; c++) {
            union { unsigned short u[16]; uint4 q[2]; } pk;
#pragma unroll
            for (int i = 0; i < 4; i++) {
                pk.u[i * 4 + 0] = f2bf(vv[c][i].x); pk.u[i * 4 + 1] = f2bf(vv[c][i].y);
                pk.u[i * 4 + 2] = f2bf(vv[c][i].z); pk.u[i * 4 + 3] = f2bf(vv[c][i].w);
            }
            *(uint4*)&mg[c * 128 + cq * 16] = pk.q[0];
            *(uint4*)&mg[c * 128 + cq * 16 + 8] = pk.q[1];
        }

        // MemGT via LDS transpose, 4 chunks of 128 d
        const int dd = t >> 1;           // 0..127 (d within chunk)
        const int jh = (t & 1) * 16;     // j half
        unsigned short* gtb = MemGT + (size_t)b * 512 * 1024 + j0 + jh;
#pragma unroll
        for (int c = 0; c < 4; c++) {
#pragma unroll
            for (int i = 0; i < 4; i++)
                *(float4*)&tileG[jj][cq * 16 + i * 4] = vv[c][i];
            __syncthreads();
            union { unsigned short u[16]; uint4 q[2]; } pt;
#pragma unroll
            for (int k = 0; k < 16; k++) pt.u[k] = f2bf(tileG[jh + k][dd]);
            unsigned short* gt = gtb + (size_t)(c * 128 + dd) * 1024;
            *(uint4*)&gt[0] = pt.q[0];
            *(uint4*)&gt[8] = pt.q[1];
            __syncthreads();
        }
    } else if (bid < 1056) {
        // ---- mask scan -> cnt/padded + rowsum zero ----
        const int b = bid - 1024;
        rowsum4[b * 256 + t] = float4{0.f, 0.f, 0.f, 0.f};
        const int* m = mask + b * 1024;
        int s = 0;
#pragma unroll
        for (int e = 0; e < 4; e++) s += (m[t * 4 + e] != 0) ? 1 : 0;
        const int lane = t & 63, wv = t >> 6;
        int x = s;
#pragma unroll
        for (int off = 1; off < 64; off <<= 1) {
            int y = __shfl_up(x, off, 64);
            if (lane >= off) x += y;
        }
        if (lane == 63) wsum[wv] = x;
        __syncthreads();
        if (t == 255) {
            int total = wsum[0] + wsum[1] + wsum[2] + wsum[3];
            cnt[b] = total;
            padded[b] = (total + 127) & ~127;
        }
    } else if (bid < 1568) {
        // ---- weight transpose ----
        const int tb = bid - 1056;
        const float* src = (tb >> 8) ? W1 : W0;
        unsigned short* dst = (tb >> 8) ? D1 : D0;
        const int rem = tb & 255;
        const int s0 = (rem & 15) * 32, d0 = (rem >> 4) * 32;
        const int tr = t >> 5, tc = t & 31;
#pragma unroll
        for (int i = 0; i < 4; i++)
            tile[tr + i * 8][tc] = src[(size_t)(s0 + tr + i * 8) * 512 + d0 + tc];
        __syncthreads();
#pragma unroll
        for (int i = 0; i < 4; i++)
            dst[(size_t)(d0 + tr + i * 8) * 512 + s0 + tc] = f2bf(tile[tc][tr + i * 8]);
    } else {
        // ---- fuse_inputs ----
        const int i = (bid - 1568) * 256 + t;   // 4194304 float4s total
        const int bq = i >> 7;
        const int d  = i & 127;
        float4 v = inputs4[i];
        out4[(size_t)bq * 256 + 128 + d] = v;
        union { unsigned short u[4]; uint2 p; } pk;
        pk.u[0] = f2bf(v.x); pk.u[1] = f2bf(v.y);
        pk.u[2] = f2bf(v.z); pk.u[3] = f2bf(v.w);
        InB16[i] = pk.p;
    }
}

// ---------------------------------------------------------------------------
// 256x256-tile, 8-wave, BK=64, 8-phase bf16 GEMM core  C = A @ Bt^T
//   (verified schedule: st-swizzle + counted vmcnt(4) + setprio)
// CMODE 0: relu -> bf16
// CMODE 1: p = (col<nbv) ? exp(acc*scale) : 0 -> bf16; rs[row] += p (atomics)
// CMODE 2: acc / rs[row] -> fp32
// ---------------------------------------------------------------------------
template<int CMODE>
__device__ __forceinline__ void gemm_core(
    unsigned char* lds,
    const unsigned short* __restrict__ Ab, const unsigned short* __restrict__ Bb,
    void* __restrict__ Cb, float* __restrict__ rs, int nbv,
    int rowA, int rowB, int Kz, int lda, int ldb, int ldc, float scale)
{
    const int nt = Kz >> 6;                 // K-tiles of 64

    const int t = threadIdx.x;
    const int w = t >> 6;                   // wave 0..7
    const int lane = t & 63;
    const int wm = w >> 2;                  // 0..1 (M half)
    const int wn = w & 3;                   // 0..3 (N quarter)
    const int l15 = lane & 15;
    // phys 16B-slot byte offset for fragment reads (swizzled)
    const int sx = (((lane >> 4) ^ ((l15 >> 1) & 3)) << 4);

    // ---- staging: thread t covers linear LDS bytes [t*16) and [t*16+8192) of
    // each 16 KiB half-tile; source pre-swizzled so swizzled reads see logical data.
    const int r0 = t >> 2;                          // row 0..127 (and +128 for 2nd load)
    const int sl = (t & 3) ^ ((t >> 3) & 3);        // logical k-slot for this dest
    const unsigned short* aS0 = Ab + (size_t)(rowA + r0) * lda + sl * 8;
    const unsigned short* aS1 = aS0 + (size_t)128 * lda;
    const unsigned short* bS0 = Bb + (size_t)(rowB + r0) * ldb + sl * 8;
    const unsigned short* bS1 = bS0 + (size_t)128 * ldb;

    const int wofs = w * 1024;                      // wave-uniform LDS dest base
    const int aRd = (wm * 128 + l15) * 64 + sx;
    const int bRd = 32768 + (wn * 64 + l15) * 64 + sx;

    f32x4 acc[8][4];
#pragma unroll
    for (int i = 0; i < 8; i++)
#pragma unroll
        for (int j = 0; j < 4; j++) acc[i][j] = f32x4{0.f, 0.f, 0.f, 0.f};

#define GLL(SRC, DOFS) __builtin_amdgcn_global_load_lds(                        \
        (const __attribute__((address_space(1))) void*)(SRC),                   \
        (__attribute__((address_space(3))) void*)&lds[DOFS], 16, 0, 0)
#define STAGEA(BUF, KH, KEL) do {                                               \
        GLL(aS0 + (KEL), (BUF) * 65536 + (KH) * 16384 + wofs);                  \
        GLL(aS1 + (KEL), (BUF) * 65536 + (KH) * 16384 + wofs + 8192); } while (0)
#define STAGEB(BUF, KH, KEL) do {                                               \
        GLL(bS0 + (KEL), (BUF) * 65536 + 32768 + (KH) * 16384 + wofs);          \
        GLL(bS1 + (KEL), (BUF) * 65536 + 32768 + (KH) * 16384 + wofs + 8192); } while (0)

    // prologue: stage tile 0 (H0=A-klo, H1=B-klo, H2=A-khi, H3=B-khi)
    STAGEA(0, 0, 0); STAGEB(0, 0, 0); STAGEA(0, 1, 32); STAGEB(0, 1, 32);
    asm volatile("s_waitcnt vmcnt(4)" ::: "memory");   // H0,H1 of tile0 landed
    __builtin_amdgcn_s_barrier();

    for (int tt = 0; tt < nt; ++tt) {
        const int cur = (tt & 1) * 65536;
        const int nxt = (tt & 1) ^ 1;
        const bool pf = (tt + 1) < nt;
        const int kn = (tt + 1) * 64;
        bf16x8 af[4], bf0[4], bf1[4];

        // ---------- phase 0: kh=0, acc rows 0-3 ----------
#pragma unroll
        for (int i = 0; i < 4; i++) af[i]  = *(const bf16x8*)&lds[cur + aRd + i * 1024];
#pragma unroll
        for (int j = 0; j < 4; j++) bf0[j] = *(const bf16x8*)&lds[cur + bRd + j * 1024];
        if (pf) STAGEA(nxt, 0, kn);
        __builtin_amdgcn_s_barrier();
        asm volatile("s_waitcnt lgkmcnt(0)" ::: "memory");
        __builtin_amdgcn_sched_barrier(0);
        __builtin_amdgcn_s_setprio(1);
#pragma unroll
        for (int i = 0; i < 4; i++)
#pragma unroll
            for (int j = 0; j < 4; j++)
                acc[i][j] = __builtin_amdgcn_mfma_f32_16x16x32_bf16(af[i], bf0[j], acc[i][j], 0, 0, 0);
        __builtin_amdgcn_s_setprio(0);
        __builtin_amdgcn_s_barrier();

        // ---------- phase 1: kh=0, acc rows 4-7 ----------
#pragma unroll
        for (int i = 0; i < 4; i++) af[i] = *(const bf16x8*)&lds[cur + aRd + (i + 4) * 1024];
        if (pf) STAGEB(nxt, 0, kn);
        __builtin_amdgcn_s_barrier();
        asm volatile("s_waitcnt lgkmcnt(0)" ::: "memory");
        __builtin_amdgcn_sched_barrier(0);
        __builtin_amdgcn_s_setprio(1);
#pragma unroll
        for (int i = 0; i < 4; i++)
#pragma unroll
            for (int j = 0; j < 4; j++)
                acc[i + 4][j] = __builtin_amdgcn_mfma_f32_16x16x32_bf16(af[i], bf0[j], acc[i + 4][j], 0, 0, 0);
        __builtin_amdgcn_s_setprio(0);
        // need H2,H3 of CURRENT tile done before phase 2 reads.
        if (pf) { asm volatile("s_waitcnt vmcnt(4)" ::: "memory"); }
        else    { asm volatile("s_waitcnt vmcnt(0)" ::: "memory"); }
        __builtin_amdgcn_s_barrier();

        // ---------- phase 2: kh=1, acc rows 0-3 ----------
#pragma unroll
        for (int i = 0; i < 4; i++) af[i]  = *(const bf16x8*)&lds[cur + 16384 + aRd + i * 1024];
#pragma unroll
        for (int j = 0; j < 4; j++) bf1[j] = *(const bf16x8*)&lds[cur + 16384 + bRd + j * 1024];
        if (pf) STAGEA(nxt, 1, kn + 32);
        __builtin_amdgcn_s_barrier();
        asm volatile("s_waitcnt lgkmcnt(0)" ::: "memory");
        __builtin_amdgcn_sched_barrier(0);
        __builtin_amdgcn_s_setprio(1);
#pragma unroll
        for (int i = 0; i < 4; i++)
#pragma unroll
            for (int j = 0; j < 4; j++)
                acc[i][j] = __builtin_amdgcn_mfma_f32_16x16x32_bf16(af[i], bf1[j], acc[i][j], 0, 0, 0);
        __builtin_amdgcn_s_setprio(0);
        __builtin_amdgcn_s_barrier();

        // ---------- phase 3: kh=1, acc rows 4-7 ----------
#pragma unroll
        for (int i = 0; i < 4; i++) af[i] = *(const bf16x8*)&lds[cur + 16384 + aRd + (i + 4) * 1024];
        if (pf) STAGEB(nxt, 1, kn + 32);
        __builtin_amdgcn_s_barrier();
        asm volatile("s_waitcnt lgkmcnt(0)" ::: "memory");
        __builtin_amdgcn_sched_barrier(0);
        __builtin_amdgcn_s_setprio(1);
#pragma unroll
        for (int i = 0; i < 4; i++)
#pragma unroll
            for (int j = 0; j < 4; j++)
                acc[i + 4][j] = __builtin_amdgcn_mfma_f32_16x16x32_bf16(af[i], bf1[j], acc[i + 4][j], 0, 0, 0);
        __builtin_amdgcn_s_setprio(0);
        // need H0,H1 of NEXT tile before its phase 0.
        if (pf) { asm volatile("s_waitcnt vmcnt(4)" ::: "memory"); }
        __builtin_amdgcn_s_barrier();
    }

#undef GLL
#undef STAGEA
#undef STAGEB

    // epilogue: C/D layout col=lane&15, row=(lane>>4)*4+reg
    const int orow = (lane >> 4) * 4;
    const int ocol = l15;

    if constexpr (CMODE == 0) {
        unsigned short* C = (unsigned short*)Cb;
#pragma unroll
        for (int mf = 0; mf < 8; mf++)
#pragma unroll
            for (int nf = 0; nf < 4; nf++) {
                const int col = rowB + wn * 64 + nf * 16 + ocol;
#pragma unroll
                for (int r = 0; r < 4; r++) {
                    const int rw = rowA + wm * 128 + mf * 16 + orow + r;
                    C[(size_t)rw * ldc + col] = f2bf(fmaxf(acc[mf][nf][r], 0.f));
                }
            }
    } else if constexpr (CMODE == 1) {
        unsigned short* C = (unsigned short*)Cb;
#pragma unroll
        for (int mf = 0; mf < 8; mf++) {
            float part[4] = {0.f, 0.f, 0.f, 0.f};
#pragma unroll
            for (int nf = 0; nf < 4; nf++) {
                const int col = rowB + wn * 64 + nf * 16 + ocol;
#pragma unroll
                for (int r = 0; r < 4; r++) {
                    float p = (col < nbv) ? __expf(acc[mf][nf][r] * scale) : 0.f;
                    part[r] += p;
                    const int rw = rowA + wm * 128 + mf * 16 + orow + r;
                    C[(size_t)rw * ldc + col] = f2bf(p);
                }
            }
#pragma unroll
            for (int r = 0; r < 4; r++) {
                float s = part[r];
                s += __shfl_xor(s, 1, 64);
                s += __shfl_xor(s, 2, 64);
                s += __shfl_xor(s, 4, 64);
                s += __shfl_xor(s, 8, 64);
                if (ocol == 0)
                    atomicAdd(&rs[rowA + wm * 128 + mf * 16 + orow + r], s);
            }
        }
    } else {  // CMODE == 2
        float* C = (float*)Cb;
#pragma unroll
        for (int mf = 0; mf < 8; mf++) {
            float inv[4];
#pragma unroll
            for (int r = 0; r < 4; r++)
                inv[r] = 1.0f / rs[rowA + wm * 128 + mf * 16 + orow + r];
#pragma unroll
            for (int nf = 0; nf < 4; nf++) {
                const int col = rowB + wn * 64 + nf * 16 + ocol;
#pragma unroll
                for (int r = 0; r < 4; r++) {
                    const int rw = rowA + wm * 128 + mf * 16 + orow + r;
                    C[(size_t)rw * ldc + col] = acc[mf][nf][r] * inv[r];
                }
            }
        }
    }
}

// ---------------------------------------------------------------------------
// Merged projection GEMMs (1-D grid of 512, XCD-swizzled so the two rowB
// halves of one A-stripe share an XCD/L2):
//   y<128 -> Xq = relu(InB16 @ Wt_in^T);  y>=128 -> Xm = relu(MemG @ Wt_mem^T)
// ---------------------------------------------------------------------------
__global__ __launch_bounds__(512, 2) void gemm_proj_kernel(
    const unsigned short* __restrict__ InB16, const unsigned short* __restrict__ WtIn,
    unsigned short* __restrict__ Xq,
    const unsigned short* __restrict__ MemG, const unsigned short* __restrict__ WtMem,
    unsigned short* __restrict__ Xm, const int* __restrict__ padded)
{
    __shared__ __align__(16) unsigned char lds[131072];
    const int id = blockIdx.x;
    const int xcd = id & 7, slot = id >> 3;
    const int y = xcd + 8 * (slot >> 1);    // 0..255, both x-halves same XCD
    const int x = slot & 1;
    const int rowB = x * 256;
    const unsigned short* A;
    const unsigned short* Bt;
    unsigned short* C;
    int rowA;
    if (y < 128) {
        A = InB16; Bt = WtIn; C = Xq; rowA = y * 256;
    } else {
        const int idx = y - 128;
        const int z = idx >> 2;
        rowA = (idx & 3) * 256;
        if (rowA >= padded[z]) return;
        A = MemG + (size_t)z * 524288;
        Bt = WtMem;
        C = Xm + (size_t)z * 524288;
    }
    gemm_core<0>(lds, A, Bt, (void*)C, nullptr, 0, rowA, rowB,
                 512, 512, 512, 512, 0.f);
}

// P = exp(Xq @ Xm^T * scale) masked; rowsum atomics.
// 1-D grid 512, XCD-swizzled: all 16 blocks of a batch on one XCD.
__global__ __launch_bounds__(512, 2) void gemm_p_kernel(
    const unsigned short* __restrict__ Xq, const unsigned short* __restrict__ Xm,
    unsigned short* __restrict__ P, const int* __restrict__ cnt,
    const int* __restrict__ padded, float* __restrict__ rowsum, float scale)
{
    __shared__ __align__(16) unsigned char lds[131072];
    const int id = blockIdx.x;
    const int xcd = id & 7, slot = id >> 3;
    const int z = xcd + 8 * (slot >> 4);    // 4 batches per XCD, 16 blocks each
    const int r = slot & 15;
    const int x = r & 3, y = r >> 2;
    const int rowB = x * 256;
    if (rowB >= padded[z]) return;
    gemm_core<1>(lds, Xq + (size_t)z * 524288, Xm + (size_t)z * 524288,
                 (void*)(P + (size_t)z * 1048576), rowsum + (size_t)z * 1024, cnt[z],
                 y * 256, rowB, 512, 512, 512, 1024, scale);
}

// context = (P @ MemGT^T) / rowsum -> fp32 out[..., 0:512]
// 1-D grid 256, XCD-swizzled: all 8 blocks of a batch on one XCD.
__global__ __launch_bounds__(512, 2) void gemm_ctx_kernel(
    const unsigned short* __restrict__ P, const unsigned short* __restrict__ MemGT,
    float* __restrict__ out, const int* __restrict__ padded, float* __restrict__ rowsum)
{
    __shared__ __align__(16) unsigned char lds[131072];
    const int id = blockIdx.x;
    const int xcd = id & 7, slot = id >> 3;
    const int z = xcd + 8 * (slot >> 3);    // 4 batches per XCD, 8 blocks each
    const int r = slot & 7;
    const int x = r & 1, y = r >> 1;
    gemm_core<2>(lds, P + (size_t)z * 1048576, MemGT + (size_t)z * 524288,
                 (void*)(out + (size_t)z * 1048576), rowsum + (size_t)z * 1024, 0,
                 y * 256, x * 256, padded[z],
                 1024, 1024, 1024, 1.f);
}

extern "C" void kernel_launch(void* const* d_in, const int* in_sizes, int n_in,
                              void* d_out, int out_size, void* d_ws, size_t ws_size,
                              hipStream_t stream)
{
    const float* inputs = (const float*)d_in[0];   // [32,1024,512]
    const float* memory = (const float*)d_in[1];   // [32,1024,512]
    const int*   mmask  = (const int*)d_in[2];     // [32,1024]
    const float* W_in   = (const float*)d_in[3];   // [512,512]
    const float* W_mem  = (const float*)d_in[4];   // [512,512]
    float* out = (float*)d_out;                    // [32,1024,1024]

    char* ws = (char*)d_ws;
    const unsigned long long MB = 1048576ull;
    unsigned short* Wt_in  = (unsigned short*)(ws);                   // 512 KiB
    unsigned short* Wt_mem = (unsigned short*)(ws + 524288);          // 512 KiB
    unsigned short* InB16  = (unsigned short*)(ws + 1 * MB);          // 32 MiB
    unsigned short* MemG   = (unsigned short*)(ws + 33 * MB);         // 32 MiB
    unsigned short* P      = (unsigned short*)(ws + 1 * MB);          // 64 MiB (alias over InB16+MemG)
    unsigned short* MemGT  = (unsigned short*)(ws + 65 * MB);         // 32 MiB
    unsigned short* Xq     = (unsigned short*)(ws + 97 * MB);         // 32 MiB
    unsigned short* Xm     = (unsigned short*)(ws + 129 * MB);        // 32 MiB
    float*          rowsum = (float*)(ws + 161 * MB);                 // 128 KiB
    int*            cntp   = (int*)(ws + 161 * MB + 262144);          // 128 B
    int*            padp   = (int*)(ws + 161 * MB + 262144 + 128);    // 128 B

    const float scale = 0.04419417382415922f;  // 1/sqrt(512)

    // 1. everything independent in one dispatch:
    //    gather (deep-ILP) + scan/rowsum + transposes + cast/concat
    prep_kernel<<<17952, 256, 0, stream>>>(
        (const float4*)inputs, (uint2*)InB16, (float4*)out,
        W_in, W_mem, Wt_in, Wt_mem,
        mmask, cntp, padp, (float4*)rowsum,
        memory, MemG, MemGT);

    // 2. both projections, XCD-swizzled
    gemm_proj_kernel<<<512, 512, 0, stream>>>(
        InB16, Wt_in, Xq, MemG, Wt_mem, Xm, padp);

    // 3. P = exp(Xq @ Xm^T * scale) for col<cnt, else 0; rowsum atomics
    gemm_p_kernel<<<512, 512, 0, stream>>>(
        Xq, Xm, P, cntp, padp, rowsum, scale);

    // 4. context = (P @ MemGT^T) / rowsum -> fp32 out[..., 0:512]
    gemm_ctx_kernel<<<256, 512, 0, stream>>>(
        P, MemGT, out, padp, rowsum);
}